// Round 3
// baseline (437.965 us; speedup 1.0000x reference)
//
#include <hip/hip_runtime.h>
#include <math.h>

#define NUM_AGENTS 256
#define HIDDEN 1024
#define RANK 32
#define NTOK 8192
#define SPLITS 4
#define RANGE (NTOK / SPLITS)   // 2048 tokens per range-split
#define TBATCH 8
#define ALPHA_MAX 5.0f
#define LN_EPS 1e-5f

// plain-vector alias: __builtin_nontemporal_* rejects HIP_vector_type
typedef float f32x4 __attribute__((ext_vector_type(4)));

// Grid: 256 agents x 4 token-range splits = 1024 blocks (= 4 blocks/CU, one
// dispatch round), 256 threads. Each block: scan its 2048-token id range,
// collect tokens of its agent (Poisson(8) expected), process in groups of 8:
//   inter[m] = h[m] . U[a];  pert[m] = inter[m] . V[a];
//   out[m] = LayerNorm(h[m] + alpha*pert[m]) * gamma + beta
//
// v3 changes (v2 was latency-bound at VGPR=48: serial U/V loads):
//  - __launch_bounds__(256,4): <=128 VGPR, 4 blocks/CU (LDS-limited 4 anyway).
//  - Explicit depth-4 double-buffered pipelines for the U and V sweeps; all
//    buffer indices resolve statically after unroll (no scratch).
//  - TBATCH=8: 2x FLOPs per loaded U/V element, half the sweeps per token.
//  - SPLITS=4: flatter Poisson tail, ~40% fewer total U/V sweeps, grid fits
//    in one round. Same-agent blocks still share an XCD (bid % 8 == agent % 8).
//  - U batch-0 prefetched before the stage barrier; V batch-0 before the
//    merge barrier (global loads cross __syncthreads legally).
__global__ __launch_bounds__(256, 4) void div_inject_kernel(
    const float* __restrict__ hglob,
    const float* __restrict__ log_alpha,
    const float* __restrict__ gamma,
    const float* __restrict__ beta,
    const float* __restrict__ U,
    const float* __restrict__ V,
    const int* __restrict__ ids,
    float* __restrict__ out)
{
    __shared__ __align__(16) float Hs[TBATCH][HIDDEN];     // 32768 B
    __shared__ __align__(16) float red[4][TBATCH][RANK];   //  4096 B (aliased below)
    __shared__ unsigned short toklist[RANGE];              //  4096 B
    // red[] lifetime plan (barrier-separated):
    //   scan:    red[3][0][0] = tokcount (read to reg before any red write)
    //   phase2:  red[w][m][r] = per-wave partial inter
    //   merge:   red[0][m][r] = inter (summed), read through phase 3
    //   LN:      red[1][0][0..63] = wred[w][s][m]  (disjoint from red[0])
    int* tokcount = (int*)&red[3][0][0];
    float* inter = &red[0][0][0];                                  // [TBATCH][RANK]
    float (*wred)[2][TBATCH] = reinterpret_cast<float (*)[2][TBATCH]>(&red[1][0][0]);

    const int t = threadIdx.x;
    const int agent = blockIdx.x & (NUM_AGENTS - 1);
    const int base = (blockIdx.x >> 8) * RANGE;

    if (t == 0) *tokcount = 0;
    __syncthreads();

    // ---- collect this agent's tokens: int4 scan over the 2048-id range ----
    #pragma unroll
    for (int w2 = 0; w2 < RANGE / 1024; ++w2) {
        int4 iv = ((const int4*)(ids + base))[t + 256 * w2];
        int ib = 4 * (t + 256 * w2);
        if ((iv.x & (NUM_AGENTS - 1)) == agent) toklist[atomicAdd(tokcount, 1)] = (unsigned short)(ib + 0);
        if ((iv.y & (NUM_AGENTS - 1)) == agent) toklist[atomicAdd(tokcount, 1)] = (unsigned short)(ib + 1);
        if ((iv.z & (NUM_AGENTS - 1)) == agent) toklist[atomicAdd(tokcount, 1)] = (unsigned short)(ib + 2);
        if ((iv.w & (NUM_AGENTS - 1)) == agent) toklist[atomicAdd(tokcount, 1)] = (unsigned short)(ib + 3);
    }
    __syncthreads();
    const int cnt = *tokcount;        // into a register before red[] is reused
    if (cnt == 0) return;

    const float alpha = fminf(__expf(log_alpha[0]), ALPHA_MAX);

    const float* Ua = U + (size_t)agent * (HIDDEN * RANK);
    const float* Va = V + (size_t)agent * (RANK * HIDDEN);

    const int r4 = (t & 7) * 4;   // rank quad: 0,4,...,28
    const int ks = t >> 3;        // k-slice 0..31
    const int c  = t * 4;         // this thread's 4 output columns
    const int wave = t >> 6, lane = t & 63;

    const float4 gv = *(const float4*)(gamma + c);
    const float4 bv = *(const float4*)(beta + c);

    for (int g = 0; g < cnt; g += TBATCH) {
        const int nm = min(TBATCH, cnt - g);
        int tk[TBATCH];
        #pragma unroll
        for (int m = 0; m < TBATCH; ++m)
            tk[m] = base + (int)toklist[g + min(m, nm - 1)];   // pad by replication

        // ---- stage TBATCH h rows into LDS (read-once: non-temporal) ----
        #pragma unroll
        for (int m = 0; m < TBATCH; ++m) {
            f32x4 hv = __builtin_nontemporal_load((const f32x4*)(hglob + (size_t)tk[m] * HIDDEN + c));
            *(f32x4*)(&Hs[m][c]) = hv;
        }

        // prefetch U batch 0 BEFORE the stage barrier (independent of Hs)
        float4 ub[2][4];
        #pragma unroll
        for (int j = 0; j < 4; ++j)
            ub[0][j] = *(const float4*)(Ua + (ks + 32 * j) * RANK + r4);

        __syncthreads();

        // ---- phase 2: inter[m][r] = sum_hh Hs[m][hh] * U[hh][r] ----
        // depth-4 double-buffered pipeline over the 32 k-slice iterations
        float4 acc[TBATCH];
        #pragma unroll
        for (int m = 0; m < TBATCH; ++m) acc[m] = make_float4(0.f, 0.f, 0.f, 0.f);
        #pragma unroll
        for (int jb = 0; jb < 8; ++jb) {
            const int cur = jb & 1;
            if (jb < 7) {
                #pragma unroll
                for (int j = 0; j < 4; ++j)
                    ub[cur ^ 1][j] = *(const float4*)(Ua + (ks + 32 * (4 * (jb + 1) + j)) * RANK + r4);
            }
            #pragma unroll
            for (int j = 0; j < 4; ++j) {
                const int hh = ks + 32 * (4 * jb + j);
                float4 u = ub[cur][j];
                #pragma unroll
                for (int m = 0; m < TBATCH; ++m) {
                    float hv = Hs[m][hh];
                    acc[m].x += hv * u.x;
                    acc[m].y += hv * u.y;
                    acc[m].z += hv * u.z;
                    acc[m].w += hv * u.w;
                }
            }
        }
        // reduce over the 8 k-slices within each wave (lane bits 3..5)
        #pragma unroll
        for (int off = 8; off <= 32; off <<= 1) {
            #pragma unroll
            for (int m = 0; m < TBATCH; ++m) {
                acc[m].x += __shfl_xor(acc[m].x, off, 64);
                acc[m].y += __shfl_xor(acc[m].y, off, 64);
                acc[m].z += __shfl_xor(acc[m].z, off, 64);
                acc[m].w += __shfl_xor(acc[m].w, off, 64);
            }
        }
        if (lane < 8) {
            #pragma unroll
            for (int m = 0; m < TBATCH; ++m)
                *(float4*)(&red[wave][m][r4]) = acc[m];
        }

        // prefetch V batch 0 BEFORE the merge barrier (overlaps merge latency)
        float4 vb[2][4];
        #pragma unroll
        for (int j = 0; j < 4; ++j)
            vb[0][j] = *(const float4*)(Va + j * HIDDEN + c);

        __syncthreads();
        {
            int m = t >> 5, rr = t & 31;
            inter[m * RANK + rr] = red[0][m][rr] + red[1][m][rr] + red[2][m][rr] + red[3][m][rr];
        }
        __syncthreads();

        // ---- phase 3: pert[m][c..c+3] = sum_r inter[m][r] * V[r][c..c+3] ----
        float4 p[TBATCH];
        #pragma unroll
        for (int m = 0; m < TBATCH; ++m) p[m] = make_float4(0.f, 0.f, 0.f, 0.f);
        #pragma unroll
        for (int rb = 0; rb < 8; ++rb) {
            const int cur = rb & 1;
            if (rb < 7) {
                #pragma unroll
                for (int j = 0; j < 4; ++j)
                    vb[cur ^ 1][j] = *(const float4*)(Va + (4 * (rb + 1) + j) * HIDDEN + c);
            }
            #pragma unroll
            for (int j = 0; j < 4; ++j) {
                const int r = 4 * rb + j;
                float4 v = vb[cur][j];
                #pragma unroll
                for (int m = 0; m < TBATCH; ++m) {
                    float ir = inter[m * RANK + r];   // LDS broadcast
                    p[m].x += ir * v.x;
                    p[m].y += ir * v.y;
                    p[m].z += ir * v.z;
                    p[m].w += ir * v.w;
                }
            }
        }

        // ---- d = h + alpha*pert; batched LayerNorm stats ----
        float4 dmv[TBATCH];
        float s[TBATCH], q[TBATCH];
        #pragma unroll
        for (int m = 0; m < TBATCH; ++m) {
            float4 hv = *(const float4*)(&Hs[m][c]);
            float4 d;
            d.x = hv.x + alpha * p[m].x;
            d.y = hv.y + alpha * p[m].y;
            d.z = hv.z + alpha * p[m].z;
            d.w = hv.w + alpha * p[m].w;
            dmv[m] = d;
            s[m] = d.x + d.y + d.z + d.w;
            q[m] = d.x * d.x + d.y * d.y + d.z * d.z + d.w * d.w;
        }
        #pragma unroll
        for (int off = 32; off > 0; off >>= 1) {
            #pragma unroll
            for (int m = 0; m < TBATCH; ++m) {
                s[m] += __shfl_xor(s[m], off, 64);
                q[m] += __shfl_xor(q[m], off, 64);
            }
        }
        if (lane == 0) {
            #pragma unroll
            for (int m = 0; m < TBATCH; ++m) {   // static indices only
                wred[wave][0][m] = s[m];
                wred[wave][1][m] = q[m];
            }
        }
        __syncthreads();

        // stats computed redundantly by every thread (LDS broadcasts; avoids a
        // second barrier + round-trip)
        float mean[TBATCH], rstd[TBATCH];
        #pragma unroll
        for (int m = 0; m < TBATCH; ++m) {
            float S = wred[0][0][m] + wred[1][0][m] + wred[2][0][m] + wred[3][0][m];
            float Q = wred[0][1][m] + wred[1][1][m] + wred[2][1][m] + wred[3][1][m];
            float mn = S * (1.0f / HIDDEN);
            mean[m] = mn;
            rstd[m] = rsqrtf(Q * (1.0f / HIDDEN) - mn * mn + LN_EPS);
        }

        // ---- normalize + write (compile-time m, uniform guard, streaming store) ----
        #pragma unroll
        for (int m = 0; m < TBATCH; ++m) {
            if (m < nm) {                         // nm is block-uniform
                float4 d = dmv[m];
                f32x4 o;
                o.x = (d.x - mean[m]) * rstd[m] * gv.x + bv.x;
                o.y = (d.y - mean[m]) * rstd[m] * gv.y + bv.y;
                o.z = (d.z - mean[m]) * rstd[m] * gv.z + bv.z;
                o.w = (d.w - mean[m]) * rstd[m] * gv.w + bv.w;
                __builtin_nontemporal_store(o, (f32x4*)(out + (size_t)tk[m] * HIDDEN + c));
            }
        }
        if (g + TBATCH < cnt) __syncthreads();    // protect Hs/red only if another group follows
    }
}

extern "C" void kernel_launch(void* const* d_in, const int* in_sizes, int n_in,
                              void* d_out, int out_size, void* d_ws, size_t ws_size,
                              hipStream_t stream) {
    const float* h     = (const float*)d_in[0];
    const float* la    = (const float*)d_in[1];
    const float* gamma = (const float*)d_in[2];
    const float* beta  = (const float*)d_in[3];
    const float* U     = (const float*)d_in[4];
    const float* V     = (const float*)d_in[5];
    const int* ids     = (const int*)d_in[6];
    float* out         = (float*)d_out;

    div_inject_kernel<<<NUM_AGENTS * SPLITS, 256, 0, stream>>>(
        h, la, gamma, beta, U, V, ids, out);
}

// Round 4
// 167.209 us; speedup vs baseline: 2.6193x; 2.6193x over previous
//
#include <hip/hip_runtime.h>
#include <math.h>

#define NUM_AGENTS 256
#define HIDDEN 1024
#define RANK 32
#define NTOK 8192
#define TBATCH 8          // tokens per compute block
#define MAXPER 128        // per-agent token-list capacity (Binomial(8192,1/256): max ~50)
#define KMAX 16           // group slots per agent (MAXPER / TBATCH)
#define ALPHA_MAX 5.0f
#define LN_EPS 1e-5f

// plain-vector alias: __builtin_nontemporal_* rejects HIP_vector_type
typedef float f32x4 __attribute__((ext_vector_type(4)));

// ---------------- kernel 1: per-agent token lists into workspace ------------
// Grid 256 blocks (one per agent), 256 threads. Each block scans all 8192 ids
// (32 KB, L2-resident after first touch) and compacts its agent's token
// indices into lists[agent][*] via an LDS atomic counter. Order within an
// agent is irrelevant (tokens independent).
__global__ __launch_bounds__(256) void scan_kernel(
    const int* __restrict__ ids, int* __restrict__ counts, int* __restrict__ lists)
{
    __shared__ int cnt;
    const int t = threadIdx.x;
    const int agent = blockIdx.x;
    if (t == 0) cnt = 0;
    __syncthreads();
    #pragma unroll
    for (int it = 0; it < NTOK / 1024; ++it) {          // 8 iters of int4
        int4 v = ((const int4*)ids)[t + 256 * it];
        int ib = 4 * (t + 256 * it);
        if ((v.x & (NUM_AGENTS - 1)) == agent) { int p = atomicAdd(&cnt, 1); if (p < MAXPER) lists[agent * MAXPER + p] = ib + 0; }
        if ((v.y & (NUM_AGENTS - 1)) == agent) { int p = atomicAdd(&cnt, 1); if (p < MAXPER) lists[agent * MAXPER + p] = ib + 1; }
        if ((v.z & (NUM_AGENTS - 1)) == agent) { int p = atomicAdd(&cnt, 1); if (p < MAXPER) lists[agent * MAXPER + p] = ib + 2; }
        if ((v.w & (NUM_AGENTS - 1)) == agent) { int p = atomicAdd(&cnt, 1); if (p < MAXPER) lists[agent * MAXPER + p] = ib + 3; }
    }
    __syncthreads();
    if (t == 0) counts[agent] = min(cnt, MAXPER);
}

// ---------------- kernel 2: one block = one group of <=8 tokens -------------
// Grid = 256 agents x KMAX slots (k-major: all k=0 blocks dispatch first, so
// guaranteed-active blocks front-load the machine; empty slots exit after one
// uniform load). Same-agent slots share an XCD (bid % 8 == agent % 8) -> the
// agent's 256 KB of U/V stays L2-warm across its groups.
//   inter[m] = h[m] . U[a];  pert[m] = inter[m] . V[a];
//   out[m] = LayerNorm(h[m] + alpha*pert[m]) * gamma + beta
// Register diet vs failed v3 (VGPR=64 + 392 MB scratch): no dmv[] (p updated
// in place), token indices in SGPRs, single group (no loop state). Peak live
// ~100 VGPR; plain launch_bounds so the RA isn't forced to spill to meet an
// occupancy cap.
__global__ __launch_bounds__(256) void div_inject_kernel(
    const float* __restrict__ hglob,
    const float* __restrict__ log_alpha,
    const float* __restrict__ gamma,
    const float* __restrict__ beta,
    const float* __restrict__ U,
    const float* __restrict__ V,
    const int* __restrict__ counts,
    const int* __restrict__ lists,
    float* __restrict__ out)
{
    __shared__ __align__(16) float Hs[TBATCH][HIDDEN];     // 32768 B
    __shared__ __align__(16) float red[4][TBATCH][RANK];   //  4096 B (aliased)
    // red[] lifetimes (barrier-separated): phase2 partials red[0..3];
    // merge writes inter=red[0] (read through phase 3); LN wred=red[1].
    float* inter = &red[0][0][0];                                   // [TBATCH][RANK]
    float (*wred)[2][TBATCH] = reinterpret_cast<float (*)[2][TBATCH]>(&red[1][0][0]);

    const int t = threadIdx.x;
    const int a = blockIdx.x & (NUM_AGENTS - 1);
    const int k = blockIdx.x >> 8;

    const int cnt = counts[a];
    const int start = k * TBATCH;
    if (start >= cnt) return;
    const int nm = min(TBATCH, cnt - start);

    // token indices: block-uniform -> SGPRs (pad by replication)
    const int* gl = lists + a * MAXPER + start;
    int tk[TBATCH];
    #pragma unroll
    for (int m = 0; m < TBATCH; ++m) tk[m] = gl[min(m, nm - 1)];

    const float alpha = fminf(__expf(log_alpha[0]), ALPHA_MAX);
    const float* Ua = U + (size_t)a * (HIDDEN * RANK);
    const float* Va = V + (size_t)a * (RANK * HIDDEN);

    const int r4 = (t & 7) * 4;   // rank quad: 0,4,...,28
    const int ks = t >> 3;        // k-slice 0..31
    const int c  = t * 4;         // this thread's 4 output columns
    const int wave = t >> 6, lane = t & 63;

    // ---- stage h rows: 8 nt loads in flight, then LDS writes ----
    {
        f32x4 hv[TBATCH];
        #pragma unroll
        for (int m = 0; m < TBATCH; ++m)
            hv[m] = __builtin_nontemporal_load((const f32x4*)(hglob + (size_t)tk[m] * HIDDEN + c));

        // prefetch U batch 0 before the stage barrier (independent of Hs)
        // (declared outside so it survives into phase 2)
        #pragma unroll
        for (int m = 0; m < TBATCH; ++m)
            *(f32x4*)(&Hs[m][c]) = hv[m];
    }
    float4 ub[2][4];
    #pragma unroll
    for (int j = 0; j < 4; ++j)
        ub[0][j] = *(const float4*)(Ua + (ks + 32 * j) * RANK + r4);
    __syncthreads();

    // ---- phase 2: inter[m][r] = sum_hh Hs[m][hh] * U[hh][r] ----
    // depth-4 double-buffered pipeline over 32 k-slice iterations
    float4 acc[TBATCH];
    #pragma unroll
    for (int m = 0; m < TBATCH; ++m) acc[m] = make_float4(0.f, 0.f, 0.f, 0.f);
    #pragma unroll
    for (int jb = 0; jb < 8; ++jb) {
        const int cur = jb & 1;
        if (jb < 7) {
            #pragma unroll
            for (int j = 0; j < 4; ++j)
                ub[cur ^ 1][j] = *(const float4*)(Ua + (ks + 32 * (4 * (jb + 1) + j)) * RANK + r4);
        }
        #pragma unroll
        for (int j = 0; j < 4; ++j) {
            const int hh = ks + 32 * (4 * jb + j);
            float4 u = ub[cur][j];
            #pragma unroll
            for (int m = 0; m < TBATCH; ++m) {
                float h0 = Hs[m][hh];
                acc[m].x += h0 * u.x;
                acc[m].y += h0 * u.y;
                acc[m].z += h0 * u.z;
                acc[m].w += h0 * u.w;
            }
        }
    }
    // reduce over the 8 k-slices within each wave (lane bits 3..5)
    #pragma unroll
    for (int off = 8; off <= 32; off <<= 1) {
        #pragma unroll
        for (int m = 0; m < TBATCH; ++m) {
            acc[m].x += __shfl_xor(acc[m].x, off, 64);
            acc[m].y += __shfl_xor(acc[m].y, off, 64);
            acc[m].z += __shfl_xor(acc[m].z, off, 64);
            acc[m].w += __shfl_xor(acc[m].w, off, 64);
        }
    }
    if (lane < 8) {
        #pragma unroll
        for (int m = 0; m < TBATCH; ++m)
            *(float4*)(&red[wave][m][r4]) = acc[m];
    }

    // prefetch V batch 0 before the merge barrier
    float4 vb[2][4];
    #pragma unroll
    for (int j = 0; j < 4; ++j)
        vb[0][j] = *(const float4*)(Va + j * HIDDEN + c);

    __syncthreads();
    {
        int m = t >> 5, rr = t & 31;
        inter[m * RANK + rr] = red[0][m][rr] + red[1][m][rr] + red[2][m][rr] + red[3][m][rr];
    }
    __syncthreads();

    // ---- phase 3: p[m][c..c+3] = sum_r inter[m][r] * V[r][c..c+3] ----
    float4 p[TBATCH];
    #pragma unroll
    for (int m = 0; m < TBATCH; ++m) p[m] = make_float4(0.f, 0.f, 0.f, 0.f);
    #pragma unroll
    for (int rb = 0; rb < 8; ++rb) {
        const int cur = rb & 1;
        if (rb < 7) {
            #pragma unroll
            for (int j = 0; j < 4; ++j)
                vb[cur ^ 1][j] = *(const float4*)(Va + (4 * (rb + 1) + j) * HIDDEN + c);
        }
        #pragma unroll
        for (int j = 0; j < 4; ++j) {
            const int r = 4 * rb + j;
            float4 v = vb[cur][j];
            #pragma unroll
            for (int m = 0; m < TBATCH; ++m) {
                float ir = inter[m * RANK + r];   // uniform LDS broadcast
                p[m].x += ir * v.x;
                p[m].y += ir * v.y;
                p[m].z += ir * v.z;
                p[m].w += ir * v.w;
            }
        }
    }

    // ---- d = h + alpha*p IN PLACE (no dmv array); LayerNorm stats ----
    float s[TBATCH], q[TBATCH];
    #pragma unroll
    for (int m = 0; m < TBATCH; ++m) {
        f32x4 h4 = *(const f32x4*)(&Hs[m][c]);
        p[m].x = h4.x + alpha * p[m].x;
        p[m].y = h4.y + alpha * p[m].y;
        p[m].z = h4.z + alpha * p[m].z;
        p[m].w = h4.w + alpha * p[m].w;
        s[m] = p[m].x + p[m].y + p[m].z + p[m].w;
        q[m] = p[m].x * p[m].x + p[m].y * p[m].y + p[m].z * p[m].z + p[m].w * p[m].w;
    }
    #pragma unroll
    for (int off = 32; off > 0; off >>= 1) {
        #pragma unroll
        for (int m = 0; m < TBATCH; ++m) {
            s[m] += __shfl_xor(s[m], off, 64);
            q[m] += __shfl_xor(q[m], off, 64);
        }
    }
    if (lane == 0) {
        #pragma unroll
        for (int m = 0; m < TBATCH; ++m) {   // static indices only
            wred[wave][0][m] = s[m];
            wred[wave][1][m] = q[m];
        }
    }
    __syncthreads();

    // stats computed redundantly by every thread (LDS broadcasts)
    const float4 gv = *(const float4*)(gamma + c);
    const float4 bv = *(const float4*)(beta + c);
    #pragma unroll
    for (int m = 0; m < TBATCH; ++m) {
        if (m < nm) {                        // nm block-uniform
            float S = wred[0][0][m] + wred[1][0][m] + wred[2][0][m] + wred[3][0][m];
            float Q = wred[0][1][m] + wred[1][1][m] + wred[2][1][m] + wred[3][1][m];
            float mean = S * (1.0f / HIDDEN);
            float rstd = rsqrtf(Q * (1.0f / HIDDEN) - mean * mean + LN_EPS);
            f32x4 o;
            o.x = (p[m].x - mean) * rstd * gv.x + bv.x;
            o.y = (p[m].y - mean) * rstd * gv.y + bv.y;
            o.z = (p[m].z - mean) * rstd * gv.z + bv.z;
            o.w = (p[m].w - mean) * rstd * gv.w + bv.w;
            __builtin_nontemporal_store(o, (f32x4*)(out + (size_t)tk[m] * HIDDEN + c));
        }
    }
}

extern "C" void kernel_launch(void* const* d_in, const int* in_sizes, int n_in,
                              void* d_out, int out_size, void* d_ws, size_t ws_size,
                              hipStream_t stream) {
    const float* h     = (const float*)d_in[0];
    const float* la    = (const float*)d_in[1];
    const float* gamma = (const float*)d_in[2];
    const float* beta  = (const float*)d_in[3];
    const float* U     = (const float*)d_in[4];
    const float* V     = (const float*)d_in[5];
    const int* ids     = (const int*)d_in[6];
    float* out         = (float*)d_out;

    int* counts = (int*)d_ws;                       // 256 ints
    int* lists  = counts + NUM_AGENTS;              // 256 x MAXPER ints (128 KB)

    scan_kernel<<<NUM_AGENTS, 256, 0, stream>>>(ids, counts, lists);
    div_inject_kernel<<<NUM_AGENTS * KMAX, 256, 0, stream>>>(
        h, la, gamma, beta, U, V, counts, lists, out);
}